// Round 3
// baseline (4107.850 us; speedup 1.0000x reference)
//
#include <hip/hip_runtime.h>

// ---------------------------------------------------------------------------
// RNN-KAN forward.  B=1024, Tx=64, IN0=256, H=512, TY=16, coeff=8.
// Output: y_pred (1024*16 f32) then h_all (1024*80*512 f32), flat.
// ---------------------------------------------------------------------------

using s16x8 = __attribute__((ext_vector_type(8))) short;
using u16x8 = __attribute__((ext_vector_type(8))) unsigned short;
using f32x4 = __attribute__((ext_vector_type(4))) float;

#define HALL_TSTRIDE 512
#define HALL_BSTRIDE (80 * 512)

__device__ __forceinline__ unsigned short f2bf(float f) {
  unsigned u = __builtin_bit_cast(unsigned, f);
  u += 0x7fffu + ((u >> 16) & 1u);   // round-to-nearest-even
  return (unsigned short)(u >> 16);
}
__device__ __forceinline__ float bf2f(unsigned short h) {
  unsigned u = ((unsigned)h) << 16;
  return __builtin_bit_cast(float, u);
}
__device__ __forceinline__ float silu(float x) {
  return x / (1.f + __expf(-x));
}
__device__ __forceinline__ float tanh_fast(float x) {
  float e2 = __expf(2.f * x);                    // inf/0 saturate correctly
  return 1.f - 2.f * __builtin_amdgcn_rcpf(e2 + 1.f);
}

// 8 cubic B-spline basis values on the uniform 12-knot grid.
__device__ __forceinline__ void basis8_f32(float xv, float g0, float invh, float* out) {
  float u = (xv - g0) * invh;
  float fs = floorf(u);
  int s = (int)fs;
  float r = u - fs;
  float omr = 1.f - r;
  float r2 = r * r, r3 = r2 * r;
  float n0 = (1.f / 6.f) * omr * omr * omr;
  float n1 = (1.f / 6.f) * (3.f * r3 - 6.f * r2 + 4.f);
  float n2 = (1.f / 6.f) * (-3.f * r3 + 3.f * r2 + 3.f * r + 1.f);
  float n3 = (1.f / 6.f) * r3;
#pragma unroll
  for (int j = 0; j < 8; ++j) {
    int d = s - j;
    out[j] = (d == 0) ? n3 : (d == 1) ? n2 : (d == 2) ? n1 : (d == 3) ? n0 : 0.f;
  }
}

__device__ __forceinline__ u16x8 basis8_bf16(float xv, float g0, float invh) {
  float t[8];
  basis8_f32(xv, g0, invh, t);
  u16x8 o;
#pragma unroll
  for (int j = 0; j < 8; ++j) o[j] = f2bf(t[j]);
  return o;
}

// ---------------------------------------------------------------------------
// Prep kernels
// ---------------------------------------------------------------------------
__global__ __launch_bounds__(256) void prep_waug(const float* __restrict__ bw,
                                                 const float* __restrict__ sw,
                                                 const float* __restrict__ sc,
                                                 unsigned short* __restrict__ Waug) {
  int o = blockIdx.x;
  for (int k = threadIdx.x; k < 2304; k += 256) {
    float v;
    if (k < 256) {
      v = bw[o * 256 + k];
    } else {
      int idx = k - 256;
      int i = idx >> 3, g = idx & 7;
      v = sw[(o * 256 + i) * 8 + g] * sc[o * 256 + i];
    }
    Waug[(long)o * 2304 + k] = f2bf(v);
  }
}

__global__ __launch_bounds__(256) void prep_whh(const float* __restrict__ w,
                                                unsigned short* __restrict__ hi,
                                                unsigned short* __restrict__ lo) {
  for (int i = blockIdx.x * 256 + threadIdx.x; i < 512 * 512; i += gridDim.x * 256) {
    float v = w[i];
    unsigned short h = f2bf(v);
    hi[i] = h;
    lo[i] = f2bf(v - bf2f(h));
  }
}

__global__ __launch_bounds__(256) void prep_i2hz(const float* __restrict__ sw,
                                                 const float* __restrict__ sc,
                                                 const float* __restrict__ grd,
                                                 float* __restrict__ i2hz) {
  int o = blockIdx.x * 256 + threadIdx.x;
  if (o < 512) {
    float g0 = grd[0];
    float invh = 1.f / (grd[1] - grd[0]);
    float bs[8];
    basis8_f32(0.f, g0, invh, bs);
    float s = 0.f;
    for (int i = 0; i < 256; ++i) {
      float a = 0.f;
#pragma unroll
      for (int j = 0; j < 8; ++j) a += bs[j] * sw[(o * 256 + i) * 8 + j];
      s += a * sc[o * 256 + i];
    }
    i2hz[o] = s;
  }
}

// ---------------------------------------------------------------------------
// Phase A: i2h GEMM.  C(65536 x 512) = A_aug(65536 x 2304) @ W_aug^T.
// 1024 blocks x 512 threads; tile 128m x 256n; 8 waves as 2x4 (64x64 each).
// ---------------------------------------------------------------------------
#define A_LD 72

__global__ __launch_bounds__(512) void kan_i2h_gemm(const float* __restrict__ x,
                                                    const float* __restrict__ grd,
                                                    const unsigned short* __restrict__ Waug,
                                                    float* __restrict__ hall) {
  __shared__ short As[128][A_LD];
  __shared__ short Bs[256][A_LD];

  int bid = blockIdx.x;
  int mt = bid >> 1;           // 512 m-tiles
  int nt = bid & 1;            // 2 n-tiles
  int m0 = mt * 128, n0 = nt * 256;
  int tid = threadIdx.x;
  int lane = tid & 63, wave = tid >> 6;   // 8 waves
  int wr = wave >> 2, wc = wave & 3;      // 2 x 4

  float g0 = grd[0];
  float invh = 1.f / (grd[1] - grd[0]);

  f32x4 acc[4][4] = {};

  int arow = tid >> 2, apart = tid & 3;   // A: 128 rows x 4 parts x 16k
  int brow = tid >> 1, bpart = tid & 1;   // B: 256 rows x 2 parts x 32k
  const float* xrow = x + (long)(m0 + arow) * 256;
  const unsigned short* wrow = Waug + (long)(n0 + brow) * 2304;

  for (int ks = 0; ks < 36; ++ks) {
    int k0 = ks * 64;
    // stage B (W_aug, bf16): 4 x u16x8 per thread
    {
      const u16x8* src = (const u16x8*)(wrow + k0 + bpart * 32);
      u16x8* dst = (u16x8*)&Bs[brow][bpart * 32];
#pragma unroll
      for (int c = 0; c < 4; ++c) dst[c] = src[c];
    }
    // stage A (computed): 16 k per thread -> 2 x u16x8
    {
      u16x8* dst = (u16x8*)&As[arow][apart * 16];
      int kA = k0 + apart * 16;
      if (k0 < 256) {
        const float* xs = xrow + kA;
#pragma unroll
        for (int c = 0; c < 2; ++c) {
          f32x4 v0 = *(const f32x4*)(xs + c * 8);
          f32x4 v1 = *(const f32x4*)(xs + c * 8 + 4);
          u16x8 pk;
#pragma unroll
          for (int e = 0; e < 4; ++e) {
            pk[e] = f2bf(silu(v0[e]));
            pk[e + 4] = f2bf(silu(v1[e]));
          }
          dst[c] = pk;
        }
      } else {
        int i0 = (kA - 256) >> 3;
        dst[0] = basis8_bf16(xrow[i0], g0, invh);
        dst[1] = basis8_bf16(xrow[i0 + 1], g0, invh);
      }
    }
    __syncthreads();
#pragma unroll
    for (int kk = 0; kk < 2; ++kk) {
      s16x8 a[4], b[4];
#pragma unroll
      for (int i = 0; i < 4; ++i)
        a[i] = *(const s16x8*)&As[wr * 64 + i * 16 + (lane & 15)][kk * 32 + (lane >> 4) * 8];
#pragma unroll
      for (int j = 0; j < 4; ++j)
        b[j] = *(const s16x8*)&Bs[wc * 64 + j * 16 + (lane & 15)][kk * 32 + (lane >> 4) * 8];
#pragma unroll
      for (int i = 0; i < 4; ++i)
#pragma unroll
        for (int j = 0; j < 4; ++j)
          acc[i][j] = __builtin_amdgcn_mfma_f32_16x16x32_bf16(a[i], b[j], acc[i][j], 0, 0, 0);
    }
    __syncthreads();
  }

  int c0 = n0 + wc * 64;
#pragma unroll
  for (int i = 0; i < 4; ++i) {
    int mbase = m0 + wr * 64 + i * 16 + ((lane >> 4) << 2);
#pragma unroll
    for (int r = 0; r < 4; ++r) {
      int m = mbase + r;
      int bb = m >> 6, tt = m & 63;
      float* orow = hall + (long)bb * HALL_BSTRIDE + (long)tt * HALL_TSTRIDE + c0;
#pragma unroll
      for (int j = 0; j < 4; ++j) orow[j * 16 + (lane & 15)] = acc[i][j][r];
    }
  }
}

// ---------------------------------------------------------------------------
// Phase B: batch-parallel persistent recurrence. 64 blocks x 512 threads.
// Block owns 16 batch rows; h in registers (split-bf16 A-frags).
// Whh hi+lo streamed L2 -> LDS via bulk global_load_lds (double-buffered
// 64 KB chunks, k-slice 32, one barrier per chunk).  No grid sync.
// LDS: 2x64KB weights + 32KB h-exchange = 160 KB.
// Weight LDS layout: row o = 128 B = 8 16B slots; logical slot q
// (q>>2 = hi/lo half, q&3 = k-8-group) stored at physical slot
// q ^ ((o>>1)&7)  -> ds_read_b128 is bank-conflict-free (verified: 8 lanes
// per 16B position).  Linear LDS dest + pre-swizzled GLOBAL source (rule 21).
// ---------------------------------------------------------------------------
__global__ __launch_bounds__(512, 2) void rnn_persist(
    const unsigned short* __restrict__ WhhHi,
    const unsigned short* __restrict__ WhhLo,
    const float* __restrict__ i2hz,
    const float* __restrict__ h2hb,
    const float* __restrict__ h0,
    float* __restrict__ hall) {
  __shared__ __align__(128) char Wbuf[2][65536];
  __shared__ __align__(16) unsigned short hH[16 * 512];
  __shared__ __align__(16) unsigned short hL[16 * 512];

  const int tid = threadIdx.x;
  const int lane = tid & 63;
  const int wave = tid >> 6;           // 0..7, owns output cols wave*64..+64
  const int m0 = blockIdx.x * 16;      // batch rows
  const int n0w = wave * 64;
  const int colg = lane & 15;          // A-row / C-col selector
  const int kgrp = lane >> 4;          // 0..3
  const int crow = kgrp * 4;           // C-row base

  // ---- weight staging source pointers (chunk-invariant part) ----
  // physical LDS byte L = wave*8192 + i*1024 + lane*16 (global_load_lds is
  // wave-uniform-base + lane*16); o = L>>7, p = (L>>4)&7, logical
  // q = p ^ ((o>>1)&7), half = q>>2, slot = q&3.
  const unsigned short* sbase[8];
#pragma unroll
  for (int i = 0; i < 8; ++i) {
    unsigned L = (unsigned)wave * 8192u + (unsigned)i * 1024u + ((unsigned)lane << 4);
    unsigned o = L >> 7;
    unsigned p = (L >> 4) & 7u;
    unsigned q = p ^ ((o >> 1) & 7u);
    sbase[i] = ((q >> 2) ? WhhLo : WhhHi) + o * 512u + (q & 3u) * 8u;
  }

  // ---- B-frag LDS byte offsets (hi at logical q=kgrp, lo at q=4+kgrp) ----
  unsigned offH[4], offL[4];
#pragma unroll
  for (int j = 0; j < 4; ++j) {
    unsigned o = (unsigned)(n0w + j * 16 + colg);
    unsigned sw = (o >> 1) & 7u;
    offH[j] = o * 128u + (((unsigned)kgrp ^ sw)) * 16u;
    offL[j] = o * 128u + (((4u + (unsigned)kgrp) ^ sw)) * 16u;
  }

  const int aswz = (colg & 7) << 4;
  const int abase0 = colg * 1024 + kgrp * 16;

  // initial A fragments from h0 (f32 -> bf16 hi/lo)
  s16x8 ah[16], al[16];
#pragma unroll
  for (int kk = 0; kk < 16; ++kk) {
    const float* src = h0 + (long)(m0 + colg) * 512 + kk * 32 + kgrp * 8;
    f32x4 v0 = *(const f32x4*)src;
    f32x4 v1 = *(const f32x4*)(src + 4);
    u16x8 hi, lo;
#pragma unroll
    for (int e = 0; e < 4; ++e) {
      unsigned short h1 = f2bf(v0[e]); hi[e] = h1; lo[e] = f2bf(v0[e] - bf2f(h1));
      unsigned short h2 = f2bf(v1[e]); hi[e + 4] = h2; lo[e + 4] = f2bf(v1[e] - bf2f(h2));
    }
    ah[kk] = __builtin_bit_cast(s16x8, hi);
    al[kk] = __builtin_bit_cast(s16x8, lo);
  }

  float bias_j[4], i2z_j[4];
#pragma unroll
  for (int j = 0; j < 4; ++j) {
    int o = n0w + j * 16 + colg;
    bias_j[j] = h2hb[o];
    i2z_j[j] = i2hz[o];
  }

  // prologue: stage chunk 0 into Wbuf[0]
  {
    char* dst = &Wbuf[0][wave * 8192];
#pragma unroll
    for (int i = 0; i < 8; ++i)
      __builtin_amdgcn_global_load_lds(
          (const __attribute__((address_space(1))) unsigned int*)(sbase[i]),
          (__attribute__((address_space(3))) unsigned int*)(dst + i * 1024), 16, 0, 0);
  }

  for (int T = 0; T < 80; ++T) {
    const bool enc = (T < 64);
    // i2h prefetch (nontemporal; lands under the chunk pipeline)
    float i2v[4][4];
#pragma unroll
    for (int r = 0; r < 4; ++r) {
      const float* hrow = hall + (long)(m0 + crow + r) * HALL_BSTRIDE + (long)T * HALL_TSTRIDE;
#pragma unroll
      for (int j = 0; j < 4; ++j)
        i2v[r][j] = enc ? __builtin_nontemporal_load(&hrow[n0w + j * 16 + colg]) : i2z_j[j];
    }

    f32x4 acc[4] = {};
#pragma unroll
    for (int c = 0; c < 16; ++c) {
      __syncthreads();   // chunk c landed (barrier drains vmcnt), all waves synced
      // stage chunk (c+1)&15 into the other buffer (overlaps chunk-c compute)
      {
        const int cn = (c + 1) & 15;
        char* dst = &Wbuf[(c + 1) & 1][wave * 8192];
#pragma unroll
        for (int i = 0; i < 8; ++i)
          __builtin_amdgcn_global_load_lds(
              (const __attribute__((address_space(1))) unsigned int*)(sbase[i] + cn * 32),
              (__attribute__((address_space(3))) unsigned int*)(dst + i * 1024), 16, 0, 0);
      }
      const char* wb = &Wbuf[c & 1][0];
      s16x8 bh[4], bl[4];
#pragma unroll
      for (int j = 0; j < 4; ++j) {
        bh[j] = *(const s16x8*)(wb + offH[j]);
        bl[j] = *(const s16x8*)(wb + offL[j]);
      }
#pragma unroll
      for (int j = 0; j < 4; ++j) {
        acc[j] = __builtin_amdgcn_mfma_f32_16x16x32_bf16(ah[c], bh[j], acc[j], 0, 0, 0);
        acc[j] = __builtin_amdgcn_mfma_f32_16x16x32_bf16(ah[c], bl[j], acc[j], 0, 0, 0);
        acc[j] = __builtin_amdgcn_mfma_f32_16x16x32_bf16(al[c], bh[j], acc[j], 0, 0, 0);
      }
    }

    // epilogue: tanh, write h_all (nt f32) + LDS (bf16 hi/lo, swizzled)
#pragma unroll
    for (int r = 0; r < 4; ++r) {
      const int row = crow + r;
      float* hrow = hall + (long)(m0 + row) * HALL_BSTRIDE + (long)T * HALL_TSTRIDE;
#pragma unroll
      for (int j = 0; j < 4; ++j) {
        const int o = n0w + j * 16 + colg;
        float pre = acc[j][r] + i2v[r][j] + bias_j[j];
        float h = tanh_fast(pre);
        __builtin_nontemporal_store(h, &hrow[o]);
        unsigned short hh = f2bf(h);
        unsigned short hl = f2bf(h - bf2f(hh));
        int boff = (row * 1024 + o * 2) ^ ((row & 7) << 4);
        *(unsigned short*)((char*)hH + boff) = hh;
        *(unsigned short*)((char*)hL + boff) = hl;
      }
    }
    __syncthreads();
    // reload A-frags (full 512-col h) from LDS
#pragma unroll
    for (int kk = 0; kk < 16; ++kk) {
      int off = (abase0 + kk * 64) ^ aswz;
      ah[kk] = *(const s16x8*)((const char*)hH + off);
      al[kk] = *(const s16x8*)((const char*)hL + off);
    }
    // next iteration's chunk-0 barrier orders these reads vs future writes
  }
}

// ---------------------------------------------------------------------------
// y_pred[b][ty] = dot(h_all[b][64+ty][:], fc_w) + fc_b   (one wave per (b,ty))
// ---------------------------------------------------------------------------
__global__ __launch_bounds__(256) void y_final(const float* __restrict__ hall,
                                               const float* __restrict__ fcw,
                                               const float* __restrict__ fcb,
                                               float* __restrict__ y) {
  int gw = (blockIdx.x * 256 + threadIdx.x) >> 6;
  int lane = threadIdx.x & 63;
  int bb = gw >> 4, ty = gw & 15;
  const float* hrow = hall + (long)bb * HALL_BSTRIDE + (long)(64 + ty) * HALL_TSTRIDE;
  float s = 0.f;
#pragma unroll
  for (int c = 0; c < 8; ++c) s += hrow[lane + c * 64] * fcw[lane + c * 64];
#pragma unroll
  for (int off = 32; off > 0; off >>= 1) s += __shfl_xor(s, off);
  if (lane == 0) y[bb * 16 + ty] = s + fcb[0];
}

// ---------------------------------------------------------------------------
extern "C" void kernel_launch(void* const* d_in, const int* in_sizes, int n_in,
                              void* d_out, int out_size, void* d_ws, size_t ws_size,
                              hipStream_t stream) {
  (void)in_sizes; (void)n_in; (void)out_size; (void)ws_size;
  const float* x   = (const float*)d_in[0];
  const float* h0  = (const float*)d_in[1];
  const float* grd = (const float*)d_in[2];
  const float* bw  = (const float*)d_in[3];
  const float* sw  = (const float*)d_in[4];
  const float* sc  = (const float*)d_in[5];
  const float* whh = (const float*)d_in[6];
  const float* hbb = (const float*)d_in[7];
  const float* fcw = (const float*)d_in[8];
  const float* fcb = (const float*)d_in[9];

  float* out = (float*)d_out;
  float* ypred = out;
  float* hall = out + 1024 * 16;

  char* ws = (char*)d_ws;
  unsigned short* Waug  = (unsigned short*)(ws);                 // 2359296 B
  unsigned short* WhhHi = (unsigned short*)(ws + 2359296);       // 524288 B
  unsigned short* WhhLo = (unsigned short*)(ws + 2883584);       // 524288 B
  float*          i2hz  = (float*)(ws + 3407872);                // 2048 B

  prep_waug<<<512, 256, 0, stream>>>(bw, sw, sc, Waug);
  prep_whh<<<512, 256, 0, stream>>>(whh, WhhHi, WhhLo);
  prep_i2hz<<<2, 256, 0, stream>>>(sw, sc, grd, i2hz);
  kan_i2h_gemm<<<1024, 512, 0, stream>>>(x, grd, Waug, hall);
  rnn_persist<<<64, 512, 0, stream>>>(WhhHi, WhhLo, i2hz, hbb, h0, hall);
  y_final<<<4096, 256, 0, stream>>>(hall, fcw, fcb, ypred);
}

// Round 4
// 1035.353 us; speedup vs baseline: 3.9676x; 3.9676x over previous
//
#include <hip/hip_runtime.h>

// ---------------------------------------------------------------------------
// RNN-KAN forward.  B=1024, Tx=64, IN0=256, H=512, TY=16, coeff=8.
// Output: y_pred (1024*16 f32) then h_all (1024*80*512 f32), flat.
// ---------------------------------------------------------------------------

using s16x8 = __attribute__((ext_vector_type(8))) short;
using u16x8 = __attribute__((ext_vector_type(8))) unsigned short;
using f32x4 = __attribute__((ext_vector_type(4))) float;
using u32x2 = __attribute__((ext_vector_type(2))) unsigned;

#define HALL_TSTRIDE 512
#define HALL_BSTRIDE (80 * 512)

__device__ __forceinline__ unsigned short f2bf(float f) {
  unsigned u = __builtin_bit_cast(unsigned, f);
  u += 0x7fffu + ((u >> 16) & 1u);   // round-to-nearest-even
  return (unsigned short)(u >> 16);
}
__device__ __forceinline__ float bf2f(unsigned short h) {
  unsigned u = ((unsigned)h) << 16;
  return __builtin_bit_cast(float, u);
}
__device__ __forceinline__ float silu(float x) {
  return x / (1.f + __expf(-x));
}
__device__ __forceinline__ float tanh_fast(float x) {
  float e2 = __expf(2.f * x);                    // inf/0 saturate correctly
  return 1.f - 2.f * __builtin_amdgcn_rcpf(e2 + 1.f);
}

// 8 cubic B-spline basis values on the uniform 12-knot grid.
__device__ __forceinline__ void basis8_f32(float xv, float g0, float invh, float* out) {
  float u = (xv - g0) * invh;
  float fs = floorf(u);
  int s = (int)fs;
  float r = u - fs;
  float omr = 1.f - r;
  float r2 = r * r, r3 = r2 * r;
  float n0 = (1.f / 6.f) * omr * omr * omr;
  float n1 = (1.f / 6.f) * (3.f * r3 - 6.f * r2 + 4.f);
  float n2 = (1.f / 6.f) * (-3.f * r3 + 3.f * r2 + 3.f * r + 1.f);
  float n3 = (1.f / 6.f) * r3;
#pragma unroll
  for (int j = 0; j < 8; ++j) {
    int d = s - j;
    out[j] = (d == 0) ? n3 : (d == 1) ? n2 : (d == 2) ? n1 : (d == 3) ? n0 : 0.f;
  }
}

__device__ __forceinline__ u16x8 basis8_bf16(float xv, float g0, float invh) {
  float t[8];
  basis8_f32(xv, g0, invh, t);
  u16x8 o;
#pragma unroll
  for (int j = 0; j < 8; ++j) o[j] = f2bf(t[j]);
  return o;
}

// ---------------------------------------------------------------------------
// Prep kernels
// ---------------------------------------------------------------------------
__global__ __launch_bounds__(256) void prep_waug(const float* __restrict__ bw,
                                                 const float* __restrict__ sw,
                                                 const float* __restrict__ sc,
                                                 unsigned short* __restrict__ Waug) {
  int o = blockIdx.x;
  for (int k = threadIdx.x; k < 2304; k += 256) {
    float v;
    if (k < 256) {
      v = bw[o * 256 + k];
    } else {
      int idx = k - 256;
      int i = idx >> 3, g = idx & 7;
      v = sw[(o * 256 + i) * 8 + g] * sc[o * 256 + i];
    }
    Waug[(long)o * 2304 + k] = f2bf(v);
  }
}

__global__ __launch_bounds__(256) void prep_whh(const float* __restrict__ w,
                                                unsigned short* __restrict__ hi,
                                                unsigned short* __restrict__ lo) {
  for (int i = blockIdx.x * 256 + threadIdx.x; i < 512 * 512; i += gridDim.x * 256) {
    float v = w[i];
    unsigned short h = f2bf(v);
    hi[i] = h;
    lo[i] = f2bf(v - bf2f(h));
  }
}

// i2h for x==0 + zero the sync counters
__global__ __launch_bounds__(256) void prep_i2hz(const float* __restrict__ sw,
                                                 const float* __restrict__ sc,
                                                 const float* __restrict__ grd,
                                                 float* __restrict__ i2hz,
                                                 unsigned* __restrict__ cnt) {
  int o = blockIdx.x * 256 + threadIdx.x;
  for (int i = o; i < 64 * 32; i += 512) cnt[i] = 0u;
  if (o < 512) {
    float g0 = grd[0];
    float invh = 1.f / (grd[1] - grd[0]);
    float bs[8];
    basis8_f32(0.f, g0, invh, bs);
    float s = 0.f;
    for (int i = 0; i < 256; ++i) {
      float a = 0.f;
#pragma unroll
      for (int j = 0; j < 8; ++j) a += bs[j] * sw[(o * 256 + i) * 8 + j];
      s += a * sc[o * 256 + i];
    }
    i2hz[o] = s;
  }
}

// ---------------------------------------------------------------------------
// Phase A: i2h GEMM.  C(65536 x 512) = A_aug(65536 x 2304) @ W_aug^T.
// 1024 blocks x 512 threads; tile 128m x 256n; 8 waves as 2x4 (64x64 each).
// ---------------------------------------------------------------------------
#define A_LD 72

__global__ __launch_bounds__(512) void kan_i2h_gemm(const float* __restrict__ x,
                                                    const float* __restrict__ grd,
                                                    const unsigned short* __restrict__ Waug,
                                                    float* __restrict__ hall) {
  __shared__ short As[128][A_LD];
  __shared__ short Bs[256][A_LD];

  int bid = blockIdx.x;
  int mt = bid >> 1;           // 512 m-tiles
  int nt = bid & 1;            // 2 n-tiles
  int m0 = mt * 128, n0 = nt * 256;
  int tid = threadIdx.x;
  int lane = tid & 63, wave = tid >> 6;   // 8 waves
  int wr = wave >> 2, wc = wave & 3;      // 2 x 4

  float g0 = grd[0];
  float invh = 1.f / (grd[1] - grd[0]);

  f32x4 acc[4][4] = {};

  int arow = tid >> 2, apart = tid & 3;   // A: 128 rows x 4 parts x 16k
  int brow = tid >> 1, bpart = tid & 1;   // B: 256 rows x 2 parts x 32k
  const float* xrow = x + (long)(m0 + arow) * 256;
  const unsigned short* wrow = Waug + (long)(n0 + brow) * 2304;

  for (int ks = 0; ks < 36; ++ks) {
    int k0 = ks * 64;
    // stage B (W_aug, bf16): 4 x u16x8 per thread
    {
      const u16x8* src = (const u16x8*)(wrow + k0 + bpart * 32);
      u16x8* dst = (u16x8*)&Bs[brow][bpart * 32];
#pragma unroll
      for (int c = 0; c < 4; ++c) dst[c] = src[c];
    }
    // stage A (computed): 16 k per thread -> 2 x u16x8
    {
      u16x8* dst = (u16x8*)&As[arow][apart * 16];
      int kA = k0 + apart * 16;
      if (k0 < 256) {
        const float* xs = xrow + kA;
#pragma unroll
        for (int c = 0; c < 2; ++c) {
          f32x4 v0 = *(const f32x4*)(xs + c * 8);
          f32x4 v1 = *(const f32x4*)(xs + c * 8 + 4);
          u16x8 pk;
#pragma unroll
          for (int e = 0; e < 4; ++e) {
            pk[e] = f2bf(silu(v0[e]));
            pk[e + 4] = f2bf(silu(v1[e]));
          }
          dst[c] = pk;
        }
      } else {
        int i0 = (kA - 256) >> 3;
        dst[0] = basis8_bf16(xrow[i0], g0, invh);
        dst[1] = basis8_bf16(xrow[i0 + 1], g0, invh);
      }
    }
    __syncthreads();
#pragma unroll
    for (int kk = 0; kk < 2; ++kk) {
      s16x8 a[4], b[4];
#pragma unroll
      for (int i = 0; i < 4; ++i)
        a[i] = *(const s16x8*)&As[wr * 64 + i * 16 + (lane & 15)][kk * 32 + (lane >> 4) * 8];
#pragma unroll
      for (int j = 0; j < 4; ++j)
        b[j] = *(const s16x8*)&Bs[wc * 64 + j * 16 + (lane & 15)][kk * 32 + (lane >> 4) * 8];
#pragma unroll
      for (int i = 0; i < 4; ++i)
#pragma unroll
        for (int j = 0; j < 4; ++j)
          acc[i][j] = __builtin_amdgcn_mfma_f32_16x16x32_bf16(a[i], b[j], acc[i][j], 0, 0, 0);
    }
    __syncthreads();
  }

  int c0 = n0 + wc * 64;
#pragma unroll
  for (int i = 0; i < 4; ++i) {
    int mbase = m0 + wr * 64 + i * 16 + ((lane >> 4) << 2);
#pragma unroll
    for (int r = 0; r < 4; ++r) {
      int m = mbase + r;
      int bb = m >> 6, tt = m & 63;
      float* orow = hall + (long)bb * HALL_BSTRIDE + (long)tt * HALL_TSTRIDE + c0;
#pragma unroll
      for (int j = 0; j < 4; ++j) orow[j * 16 + (lane & 15)] = acc[i][j][r];
    }
  }
}

// ---------------------------------------------------------------------------
// Phase B: VGPR-resident-weight recurrence.  Grid = 256 blocks (all CUs):
// 64 batch-groups (g) x 4 col-groups (cg).  Block: 16 rows x 128 cols,
// 8 waves; each wave holds its 16 cols of Whh hi+lo in 128 VGPRs (loaded
// once).  h (16x512 hi/lo bf16) in 32 KB XOR-swizzled LDS.
// Per-step cross-block h exchange: coherent (sc0 sc1) stores to hall,
// one release-atomicAdd per block on cnt[g], siblings spin on a RELAXED
// atomic load (never acquire -> no buffer_inv), then coherent dwordx4
// loads refill the LDS h arrays.  Counters are monotonic (4 per step).
// ---------------------------------------------------------------------------
__device__ __forceinline__ void pack_write_h(f32x4 v, int rr, int c16,
                                             char* hHb, char* hLb) {
  unsigned h0 = f2bf(v[0]), h1 = f2bf(v[1]), h2 = f2bf(v[2]), h3 = f2bf(v[3]);
  unsigned l0 = f2bf(v[0] - bf2f((unsigned short)h0));
  unsigned l1 = f2bf(v[1] - bf2f((unsigned short)h1));
  unsigned l2 = f2bf(v[2] - bf2f((unsigned short)h2));
  unsigned l3 = f2bf(v[3] - bf2f((unsigned short)h3));
  u32x2 hw, lw;
  hw[0] = h0 | (h1 << 16); hw[1] = h2 | (h3 << 16);
  lw[0] = l0 | (l1 << 16); lw[1] = l2 | (l3 << 16);
  int byte = (rr * 1024 + c16 * 8) ^ ((rr & 7) << 4);
  *(u32x2*)(hHb + byte) = hw;
  *(u32x2*)(hLb + byte) = lw;
}

__global__ __launch_bounds__(512, 2) void rnn_persist(
    const unsigned short* __restrict__ WhhHi,
    const unsigned short* __restrict__ WhhLo,
    const float* __restrict__ i2hz,
    const float* __restrict__ h2hb,
    const float* __restrict__ h0,
    float* __restrict__ hall,
    unsigned* __restrict__ cnt) {
  __shared__ __align__(16) char hHb[16 * 1024];
  __shared__ __align__(16) char hLb[16 * 1024];

  const int tid = threadIdx.x;
  const int lane = tid & 63;
  const int wave = tid >> 6;            // 0..7
  const int bid = blockIdx.x;
  const int cg = bid & 3;               // col-group
  const int g = bid >> 2;               // batch-group
  const int m0 = g * 16;                // batch rows
  const int colg = lane & 15;
  const int kgrp = lane >> 4;           // 0..3
  const int o = cg * 128 + wave * 16 + colg;   // this lane's output col
  const int aswz = (colg & 7) << 4;

  // ---- load this wave's weight slice into VGPRs (once) ----
  s16x8 wh[16], wl[16];
#pragma unroll
  for (int kk = 0; kk < 16; ++kk) {
    long woff = (long)o * 512 + kk * 32 + kgrp * 8;
    wh[kk] = *(const s16x8*)(WhhHi + woff);
    wl[kk] = *(const s16x8*)(WhhLo + woff);
  }
  const float bias = h2hb[o];
  const float i2z = i2hz[o];

  // ---- prologue: h0 -> LDS (hi/lo, swizzled) ----
  {
    const int rr = tid >> 5, cc = tid & 31;
#pragma unroll
    for (int j = 0; j < 4; ++j) {
      int c16 = cc + j * 32;
      f32x4 v = *(const f32x4*)(h0 + (long)(m0 + rr) * 512 + c16 * 4);
      pack_write_h(v, rr, c16, hHb, hLb);
    }
  }
  __syncthreads();

  for (int T = 0; T < 80; ++T) {
    // issue i2h coherent loads early (land under MFMA loop)
    float i2v[4];
    if (T < 64) {
#pragma unroll
      for (int r = 0; r < 4; ++r) {
        const float* p = hall + (long)(m0 + kgrp * 4 + r) * HALL_BSTRIDE +
                         (long)T * HALL_TSTRIDE + o;
        asm volatile("global_load_dword %0, %1, off sc0 sc1" : "=v"(i2v[r]) : "v"(p));
      }
    }

    f32x4 aA = {}, aB = {}, aC = {};
#pragma unroll
    for (int kk = 0; kk < 16; ++kk) {
      int abyte = (colg * 1024 + kk * 64 + kgrp * 16) ^ aswz;
      s16x8 ah = *(const s16x8*)(hHb + abyte);
      s16x8 al = *(const s16x8*)(hLb + abyte);
      aA = __builtin_amdgcn_mfma_f32_16x16x32_bf16(ah, wh[kk], aA, 0, 0, 0);
      aB = __builtin_amdgcn_mfma_f32_16x16x32_bf16(ah, wl[kk], aB, 0, 0, 0);
      aC = __builtin_amdgcn_mfma_f32_16x16x32_bf16(al, wh[kk], aC, 0, 0, 0);
    }

    if (T < 64) {
      asm volatile("s_waitcnt vmcnt(0)" ::: "memory");
      __builtin_amdgcn_sched_barrier(0);
    } else {
#pragma unroll
      for (int r = 0; r < 4; ++r) i2v[r] = i2z;
    }

    // epilogue: tanh + coherent store of h into hall
#pragma unroll
    for (int r = 0; r < 4; ++r) {
      float pre = aA[r] + aB[r] + aC[r] + i2v[r] + bias;
      float h = tanh_fast(pre);
      float* p = hall + (long)(m0 + kgrp * 4 + r) * HALL_BSTRIDE +
                 (long)T * HALL_TSTRIDE + o;
      asm volatile("global_store_dword %0, %1, off sc0 sc1" :: "v"(p), "v"(h) : "memory");
    }

    if (T == 79) break;

    asm volatile("s_waitcnt vmcnt(0)" ::: "memory");
    __syncthreads();                       // all waves' stores complete
    if (tid == 0)
      __hip_atomic_fetch_add(&cnt[g * 32], 1u, __ATOMIC_RELEASE,
                             __HIP_MEMORY_SCOPE_AGENT);
    if (tid == 0) {
      unsigned tgt = 4u * (unsigned)(T + 1);
      while (__hip_atomic_load(&cnt[g * 32], __ATOMIC_RELAXED,
                               __HIP_MEMORY_SCOPE_AGENT) < tgt)
        __builtin_amdgcn_s_sleep(2);
    }
    __syncthreads();

    // A-refill: coherent loads of h_T (16 rows x 512) -> LDS hi/lo
    {
      const int rr = tid >> 5, cc = tid & 31;
      const float* src = hall + (long)(m0 + rr) * HALL_BSTRIDE + (long)T * HALL_TSTRIDE;
      f32x4 v[4];
#pragma unroll
      for (int j = 0; j < 4; ++j) {
        const float* p = src + (cc + j * 32) * 4;
        asm volatile("global_load_dwordx4 %0, %1, off sc0 sc1" : "=v"(v[j]) : "v"(p));
      }
      asm volatile("s_waitcnt vmcnt(0)" ::: "memory");
      __builtin_amdgcn_sched_barrier(0);
#pragma unroll
      for (int j = 0; j < 4; ++j) pack_write_h(v[j], rr, cc + j * 32, hHb, hLb);
    }
    __syncthreads();
  }
}

// ---------------------------------------------------------------------------
// y_pred[b][ty] = dot(h_all[b][64+ty][:], fc_w) + fc_b   (one wave per (b,ty))
// ---------------------------------------------------------------------------
__global__ __launch_bounds__(256) void y_final(const float* __restrict__ hall,
                                               const float* __restrict__ fcw,
                                               const float* __restrict__ fcb,
                                               float* __restrict__ y) {
  int gw = (blockIdx.x * 256 + threadIdx.x) >> 6;
  int lane = threadIdx.x & 63;
  int bb = gw >> 4, ty = gw & 15;
  const float* hrow = hall + (long)bb * HALL_BSTRIDE + (long)(64 + ty) * HALL_TSTRIDE;
  float s = 0.f;
#pragma unroll
  for (int c = 0; c < 8; ++c) s += hrow[lane + c * 64] * fcw[lane + c * 64];
#pragma unroll
  for (int off = 32; off > 0; off >>= 1) s += __shfl_xor(s, off);
  if (lane == 0) y[bb * 16 + ty] = s + fcb[0];
}

// ---------------------------------------------------------------------------
extern "C" void kernel_launch(void* const* d_in, const int* in_sizes, int n_in,
                              void* d_out, int out_size, void* d_ws, size_t ws_size,
                              hipStream_t stream) {
  (void)in_sizes; (void)n_in; (void)out_size; (void)ws_size;
  const float* x   = (const float*)d_in[0];
  const float* h0  = (const float*)d_in[1];
  const float* grd = (const float*)d_in[2];
  const float* bw  = (const float*)d_in[3];
  const float* sw  = (const float*)d_in[4];
  const float* sc  = (const float*)d_in[5];
  const float* whh = (const float*)d_in[6];
  const float* hbb = (const float*)d_in[7];
  const float* fcw = (const float*)d_in[8];
  const float* fcb = (const float*)d_in[9];

  float* out = (float*)d_out;
  float* ypred = out;
  float* hall = out + 1024 * 16;

  char* ws = (char*)d_ws;
  unsigned short* Waug  = (unsigned short*)(ws);                 // 2359296 B
  unsigned short* WhhHi = (unsigned short*)(ws + 2359296);       // 524288 B
  unsigned short* WhhLo = (unsigned short*)(ws + 2883584);       // 524288 B
  float*          i2hz  = (float*)(ws + 3407872);                // 2048 B
  unsigned*       cnt   = (unsigned*)(ws + 3409920);             // 64*32 u32

  prep_waug<<<512, 256, 0, stream>>>(bw, sw, sc, Waug);
  prep_whh<<<512, 256, 0, stream>>>(whh, WhhHi, WhhLo);
  prep_i2hz<<<2, 256, 0, stream>>>(sw, sc, grd, i2hz, cnt);
  kan_i2h_gemm<<<1024, 512, 0, stream>>>(x, grd, Waug, hall);
  rnn_persist<<<256, 512, 0, stream>>>(WhhHi, WhhLo, i2hz, hbb, h0, hall, cnt);
  y_final<<<4096, 256, 0, stream>>>(hall, fcw, fcb, ypred);
}

// Round 6
// 795.291 us; speedup vs baseline: 5.1652x; 1.3019x over previous
//
#include <hip/hip_runtime.h>

// ---------------------------------------------------------------------------
// RNN-KAN forward.  B=1024, Tx=64, IN0=256, H=512, TY=16, coeff=8.
// Output: y_pred (1024*16 f32) then h_all (1024*80*512 f32), flat.
// ---------------------------------------------------------------------------

using s16x8 = __attribute__((ext_vector_type(8))) short;
using u16x8 = __attribute__((ext_vector_type(8))) unsigned short;
using f32x4 = __attribute__((ext_vector_type(4))) float;
using u32x2 = __attribute__((ext_vector_type(2))) unsigned;

#define HALL_TSTRIDE 512
#define HALL_BSTRIDE (80 * 512)

__device__ __forceinline__ unsigned short f2bf(float f) {
  unsigned u = __builtin_bit_cast(unsigned, f);
  u += 0x7fffu + ((u >> 16) & 1u);   // round-to-nearest-even
  return (unsigned short)(u >> 16);
}
__device__ __forceinline__ float bf2f(unsigned short h) {
  unsigned u = ((unsigned)h) << 16;
  return __builtin_bit_cast(float, u);
}
__device__ __forceinline__ float silu(float x) {
  return x / (1.f + __expf(-x));
}
__device__ __forceinline__ float tanh_fast(float x) {
  float e2 = __expf(2.f * x);                    // inf/0 saturate correctly
  return 1.f - 2.f * __builtin_amdgcn_rcpf(e2 + 1.f);
}

// 8 cubic B-spline basis values on the uniform 12-knot grid.
__device__ __forceinline__ void basis8_f32(float xv, float g0, float invh, float* out) {
  float u = (xv - g0) * invh;
  float fs = floorf(u);
  int s = (int)fs;
  float r = u - fs;
  float omr = 1.f - r;
  float r2 = r * r, r3 = r2 * r;
  float n0 = (1.f / 6.f) * omr * omr * omr;
  float n1 = (1.f / 6.f) * (3.f * r3 - 6.f * r2 + 4.f);
  float n2 = (1.f / 6.f) * (-3.f * r3 + 3.f * r2 + 3.f * r + 1.f);
  float n3 = (1.f / 6.f) * r3;
#pragma unroll
  for (int j = 0; j < 8; ++j) {
    int d = s - j;
    out[j] = (d == 0) ? n3 : (d == 1) ? n2 : (d == 2) ? n1 : (d == 3) ? n0 : 0.f;
  }
}

__device__ __forceinline__ u16x8 basis8_bf16(float xv, float g0, float invh) {
  float t[8];
  basis8_f32(xv, g0, invh, t);
  u16x8 o;
#pragma unroll
  for (int j = 0; j < 8; ++j) o[j] = f2bf(t[j]);
  return o;
}

// ---------------------------------------------------------------------------
// Prep kernels
// ---------------------------------------------------------------------------
__global__ __launch_bounds__(256) void prep_waug(const float* __restrict__ bw,
                                                 const float* __restrict__ sw,
                                                 const float* __restrict__ sc,
                                                 unsigned short* __restrict__ Waug) {
  int o = blockIdx.x;
  for (int k = threadIdx.x; k < 2304; k += 256) {
    float v;
    if (k < 256) {
      v = bw[o * 256 + k];
    } else {
      int idx = k - 256;
      int i = idx >> 3, g = idx & 7;
      v = sw[(o * 256 + i) * 8 + g] * sc[o * 256 + i];
    }
    Waug[(long)o * 2304 + k] = f2bf(v);
  }
}

__global__ __launch_bounds__(256) void prep_whh(const float* __restrict__ w,
                                                unsigned short* __restrict__ hi,
                                                unsigned short* __restrict__ lo) {
  for (int i = blockIdx.x * 256 + threadIdx.x; i < 512 * 512; i += gridDim.x * 256) {
    float v = w[i];
    unsigned short h = f2bf(v);
    hi[i] = h;
    lo[i] = f2bf(v - bf2f(h));
  }
}

// i2h for x==0 + zero the sync counters
__global__ __launch_bounds__(256) void prep_i2hz(const float* __restrict__ sw,
                                                 const float* __restrict__ sc,
                                                 const float* __restrict__ grd,
                                                 float* __restrict__ i2hz,
                                                 unsigned* __restrict__ cnt) {
  int o = blockIdx.x * 256 + threadIdx.x;
  for (int i = o; i < 64 * 32; i += 512) cnt[i] = 0u;
  if (o < 512) {
    float g0 = grd[0];
    float invh = 1.f / (grd[1] - grd[0]);
    float bs[8];
    basis8_f32(0.f, g0, invh, bs);
    float s = 0.f;
    for (int i = 0; i < 256; ++i) {
      float a = 0.f;
#pragma unroll
      for (int j = 0; j < 8; ++j) a += bs[j] * sw[(o * 256 + i) * 8 + j];
      s += a * sc[o * 256 + i];
    }
    i2hz[o] = s;
  }
}

// ---------------------------------------------------------------------------
// Phase A: i2h GEMM.  C(65536 x 512) = A_aug(65536 x 2304) @ W_aug^T.
// 1024 blocks x 512 threads; tile 128m x 256n; 8 waves as 2x4 (64x64 each).
// ---------------------------------------------------------------------------
#define A_LD 72

__global__ __launch_bounds__(512) void kan_i2h_gemm(const float* __restrict__ x,
                                                    const float* __restrict__ grd,
                                                    const unsigned short* __restrict__ Waug,
                                                    float* __restrict__ hall) {
  __shared__ short As[128][A_LD];
  __shared__ short Bs[256][A_LD];

  int bid = blockIdx.x;
  int mt = bid >> 1;           // 512 m-tiles
  int nt = bid & 1;            // 2 n-tiles
  int m0 = mt * 128, n0 = nt * 256;
  int tid = threadIdx.x;
  int lane = tid & 63, wave = tid >> 6;   // 8 waves
  int wr = wave >> 2, wc = wave & 3;      // 2 x 4

  float g0 = grd[0];
  float invh = 1.f / (grd[1] - grd[0]);

  f32x4 acc[4][4] = {};

  int arow = tid >> 2, apart = tid & 3;   // A: 128 rows x 4 parts x 16k
  int brow = tid >> 1, bpart = tid & 1;   // B: 256 rows x 2 parts x 32k
  const float* xrow = x + (long)(m0 + arow) * 256;
  const unsigned short* wrow = Waug + (long)(n0 + brow) * 2304;

  for (int ks = 0; ks < 36; ++ks) {
    int k0 = ks * 64;
    // stage B (W_aug, bf16): 4 x u16x8 per thread
    {
      const u16x8* src = (const u16x8*)(wrow + k0 + bpart * 32);
      u16x8* dst = (u16x8*)&Bs[brow][bpart * 32];
#pragma unroll
      for (int c = 0; c < 4; ++c) dst[c] = src[c];
    }
    // stage A (computed): 16 k per thread -> 2 x u16x8
    {
      u16x8* dst = (u16x8*)&As[arow][apart * 16];
      int kA = k0 + apart * 16;
      if (k0 < 256) {
        const float* xs = xrow + kA;
#pragma unroll
        for (int c = 0; c < 2; ++c) {
          f32x4 v0 = *(const f32x4*)(xs + c * 8);
          f32x4 v1 = *(const f32x4*)(xs + c * 8 + 4);
          u16x8 pk;
#pragma unroll
          for (int e = 0; e < 4; ++e) {
            pk[e] = f2bf(silu(v0[e]));
            pk[e + 4] = f2bf(silu(v1[e]));
          }
          dst[c] = pk;
        }
      } else {
        int i0 = (kA - 256) >> 3;
        dst[0] = basis8_bf16(xrow[i0], g0, invh);
        dst[1] = basis8_bf16(xrow[i0 + 1], g0, invh);
      }
    }
    __syncthreads();
#pragma unroll
    for (int kk = 0; kk < 2; ++kk) {
      s16x8 a[4], b[4];
#pragma unroll
      for (int i = 0; i < 4; ++i)
        a[i] = *(const s16x8*)&As[wr * 64 + i * 16 + (lane & 15)][kk * 32 + (lane >> 4) * 8];
#pragma unroll
      for (int j = 0; j < 4; ++j)
        b[j] = *(const s16x8*)&Bs[wc * 64 + j * 16 + (lane & 15)][kk * 32 + (lane >> 4) * 8];
#pragma unroll
      for (int i = 0; i < 4; ++i)
#pragma unroll
        for (int j = 0; j < 4; ++j)
          acc[i][j] = __builtin_amdgcn_mfma_f32_16x16x32_bf16(a[i], b[j], acc[i][j], 0, 0, 0);
    }
    __syncthreads();
  }

  int c0 = n0 + wc * 64;
#pragma unroll
  for (int i = 0; i < 4; ++i) {
    int mbase = m0 + wr * 64 + i * 16 + ((lane >> 4) << 2);
#pragma unroll
    for (int r = 0; r < 4; ++r) {
      int m = mbase + r;
      int bb = m >> 6, tt = m & 63;
      float* orow = hall + (long)bb * HALL_BSTRIDE + (long)tt * HALL_TSTRIDE + c0;
#pragma unroll
      for (int j = 0; j < 4; ++j) orow[j * 16 + (lane & 15)] = acc[i][j][r];
    }
  }
}

// ---------------------------------------------------------------------------
// Phase B: VGPR-pinned-weight recurrence.  R4's proven structure: 256 blocks
// x 512 threads (1 block/CU, co-residency guaranteed), block = 16 batch rows
// x 128 cols, 8 waves x 16 cols.  ONE change vs R4: each wave's Whh hi+lo
// slice (128 VGPRs) is pinned via asm-volatile loads so the compiler cannot
// re-stream it from L2 every step (R4 counters: VGPR=100 < 128 proved it
// re-loaded).  __launch_bounds__(512,2) -> 256-VGPR cap, ~190 used, no spill.
// Sibling decode places each group's 4 col-blocks on ONE XCD.
// Exchange: identical fence-free scheme as R4 (sc0 sc1 stores, release-
// atomic + relaxed spin, sc0 sc1 refill loads).
// ---------------------------------------------------------------------------
__device__ __forceinline__ void pack_write_h(f32x4 v, int rr, int c16,
                                             char* hHb, char* hLb) {
  unsigned h0 = f2bf(v[0]), h1 = f2bf(v[1]), h2 = f2bf(v[2]), h3 = f2bf(v[3]);
  unsigned l0 = f2bf(v[0] - bf2f((unsigned short)h0));
  unsigned l1 = f2bf(v[1] - bf2f((unsigned short)h1));
  unsigned l2 = f2bf(v[2] - bf2f((unsigned short)h2));
  unsigned l3 = f2bf(v[3] - bf2f((unsigned short)h3));
  u32x2 hw, lw;
  hw[0] = h0 | (h1 << 16); hw[1] = h2 | (h3 << 16);
  lw[0] = l0 | (l1 << 16); lw[1] = l2 | (l3 << 16);
  int byte = (rr * 1024 + c16 * 8) ^ ((rr & 7) << 4);
  *(u32x2*)(hHb + byte) = hw;
  *(u32x2*)(hLb + byte) = lw;
}

__global__ __launch_bounds__(512, 2) void rnn_persist(
    const unsigned short* __restrict__ WhhHi,
    const unsigned short* __restrict__ WhhLo,
    const float* __restrict__ i2hz,
    const float* __restrict__ h2hb,
    const float* __restrict__ h0,
    float* __restrict__ hall,
    unsigned* __restrict__ cnt) {
  __shared__ __align__(16) char hHb[16 * 1024];
  __shared__ __align__(16) char hLb[16 * 1024];

  const int tid = threadIdx.x;
  const int lane = tid & 63;
  const int wave = tid >> 6;            // 0..7
  const int bid = blockIdx.x;
  // XCD-local grouping: the 4 col-siblings of a batch-group share bid%8
  const int xcd = bid & 7;              // XCD (round-robin dispatch)
  const int j = bid >> 3;               // 0..31
  const int cg = j & 3;                 // col-group
  const int g = xcd * 8 + (j >> 2);     // batch-group 0..63
  const int m0 = g * 16;                // batch rows
  const int colg = lane & 15;
  const int kgrp = lane >> 4;           // 0..3
  const int o = cg * 128 + wave * 16 + colg;   // this lane's output col
  const int aswz = (colg & 7) << 4;

  // ---- pin this wave's weight slice in VGPRs (asm: not rematerializable) --
  s16x8 wh[16], wl[16];
#pragma unroll
  for (int kk = 0; kk < 16; ++kk) {
    const unsigned short* ph = WhhHi + (long)o * 512 + kk * 32 + kgrp * 8;
    const unsigned short* pl = WhhLo + (long)o * 512 + kk * 32 + kgrp * 8;
    asm volatile("global_load_dwordx4 %0, %1, off" : "=v"(wh[kk]) : "v"(ph));
    asm volatile("global_load_dwordx4 %0, %1, off" : "=v"(wl[kk]) : "v"(pl));
  }
  const float bias = h2hb[o];
  const float i2z = i2hz[o];
  asm volatile("s_waitcnt vmcnt(0)" ::: "memory");
  __builtin_amdgcn_sched_barrier(0);

  // ---- prologue: h0 -> LDS (hi/lo, swizzled) ----
  {
    const int rr = tid >> 5, cc = tid & 31;
#pragma unroll
    for (int jj = 0; jj < 4; ++jj) {
      int c16 = cc + jj * 32;
      f32x4 v = *(const f32x4*)(h0 + (long)(m0 + rr) * 512 + c16 * 4);
      pack_write_h(v, rr, c16, hHb, hLb);
    }
  }
  __syncthreads();

  for (int T = 0; T < 80; ++T) {
    // issue i2h coherent loads early (land under MFMA loop)
    float i2v[4];
    if (T < 64) {
#pragma unroll
      for (int r = 0; r < 4; ++r) {
        const float* p = hall + (long)(m0 + kgrp * 4 + r) * HALL_BSTRIDE +
                         (long)T * HALL_TSTRIDE + o;
        asm volatile("global_load_dword %0, %1, off sc0 sc1" : "=v"(i2v[r]) : "v"(p));
      }
    }

    f32x4 aA = {}, aB = {}, aC = {};
#pragma unroll
    for (int kk = 0; kk < 16; ++kk) {
      int abyte = (colg * 1024 + kk * 64 + kgrp * 16) ^ aswz;
      s16x8 ah = *(const s16x8*)(hHb + abyte);
      s16x8 al = *(const s16x8*)(hLb + abyte);
      aA = __builtin_amdgcn_mfma_f32_16x16x32_bf16(ah, wh[kk], aA, 0, 0, 0);
      aB = __builtin_amdgcn_mfma_f32_16x16x32_bf16(ah, wl[kk], aB, 0, 0, 0);
      aC = __builtin_amdgcn_mfma_f32_16x16x32_bf16(al, wh[kk], aC, 0, 0, 0);
    }

    if (T < 64) {
      asm volatile("s_waitcnt vmcnt(0)" ::: "memory");
      __builtin_amdgcn_sched_barrier(0);
    } else {
#pragma unroll
      for (int r = 0; r < 4; ++r) i2v[r] = i2z;
    }

    // epilogue: tanh + coherent store of h into hall
#pragma unroll
    for (int r = 0; r < 4; ++r) {
      float pre = aA[r] + aB[r] + aC[r] + i2v[r] + bias;
      float h = tanh_fast(pre);
      float* p = hall + (long)(m0 + kgrp * 4 + r) * HALL_BSTRIDE +
                 (long)T * HALL_TSTRIDE + o;
      asm volatile("global_store_dword %0, %1, off sc0 sc1" :: "v"(p), "v"(h) : "memory");
    }

    if (T == 79) break;

    asm volatile("s_waitcnt vmcnt(0)" ::: "memory");
    __syncthreads();                       // all waves' stores complete
    if (tid == 0) {
      __hip_atomic_fetch_add(&cnt[g * 32], 1u, __ATOMIC_RELEASE,
                             __HIP_MEMORY_SCOPE_AGENT);
      unsigned tgt = 4u * (unsigned)(T + 1);
      while (__hip_atomic_load(&cnt[g * 32], __ATOMIC_RELAXED,
                               __HIP_MEMORY_SCOPE_AGENT) < tgt)
        __builtin_amdgcn_s_sleep(2);
    }
    __syncthreads();

    // A-refill: coherent loads of h_T (16 rows x 512) -> LDS hi/lo
    {
      const int rr = tid >> 5, cc = tid & 31;
      const float* src = hall + (long)(m0 + rr) * HALL_BSTRIDE + (long)T * HALL_TSTRIDE;
      f32x4 v[4];
#pragma unroll
      for (int jj = 0; jj < 4; ++jj) {
        const float* p = src + (cc + jj * 32) * 4;
        asm volatile("global_load_dwordx4 %0, %1, off sc0 sc1" : "=v"(v[jj]) : "v"(p));
      }
      asm volatile("s_waitcnt vmcnt(0)" ::: "memory");
      __builtin_amdgcn_sched_barrier(0);
#pragma unroll
      for (int jj = 0; jj < 4; ++jj) pack_write_h(v[jj], rr, cc + jj * 32, hHb, hLb);
    }
    __syncthreads();
  }
}

// ---------------------------------------------------------------------------
// y_pred[b][ty] = dot(h_all[b][64+ty][:], fc_w) + fc_b   (one wave per (b,ty))
// ---------------------------------------------------------------------------
__global__ __launch_bounds__(256) void y_final(const float* __restrict__ hall,
                                               const float* __restrict__ fcw,
                                               const float* __restrict__ fcb,
                                               float* __restrict__ y) {
  int gw = (blockIdx.x * 256 + threadIdx.x) >> 6;
  int lane = threadIdx.x & 63;
  int bb = gw >> 4, ty = gw & 15;
  const float* hrow = hall + (long)bb * HALL_BSTRIDE + (long)(64 + ty) * HALL_TSTRIDE;
  float s = 0.f;
#pragma unroll
  for (int c = 0; c < 8; ++c) s += hrow[lane + c * 64] * fcw[lane + c * 64];
#pragma unroll
  for (int off = 32; off > 0; off >>= 1) s += __shfl_xor(s, off);
  if (lane == 0) y[bb * 16 + ty] = s + fcb[0];
}

// ---------------------------------------------------------------------------
extern "C" void kernel_launch(void* const* d_in, const int* in_sizes, int n_in,
                              void* d_out, int out_size, void* d_ws, size_t ws_size,
                              hipStream_t stream) {
  (void)in_sizes; (void)n_in; (void)out_size; (void)ws_size;
  const float* x   = (const float*)d_in[0];
  const float* h0  = (const float*)d_in[1];
  const float* grd = (const float*)d_in[2];
  const float* bw  = (const float*)d_in[3];
  const float* sw  = (const float*)d_in[4];
  const float* sc  = (const float*)d_in[5];
  const float* whh = (const float*)d_in[6];
  const float* hbb = (const float*)d_in[7];
  const float* fcw = (const float*)d_in[8];
  const float* fcb = (const float*)d_in[9];

  float* out = (float*)d_out;
  float* ypred = out;
  float* hall = out + 1024 * 16;

  char* ws = (char*)d_ws;
  unsigned short* Waug  = (unsigned short*)(ws);                 // 2359296 B
  unsigned short* WhhHi = (unsigned short*)(ws + 2359296);       // 524288 B
  unsigned short* WhhLo = (unsigned short*)(ws + 2883584);       // 524288 B
  float*          i2hz  = (float*)(ws + 3407872);                // 2048 B
  unsigned*       cnt   = (unsigned*)(ws + 3409920);             // 64*32 u32

  prep_waug<<<512, 256, 0, stream>>>(bw, sw, sc, Waug);
  prep_whh<<<512, 256, 0, stream>>>(whh, WhhHi, WhhLo);
  prep_i2hz<<<2, 256, 0, stream>>>(sw, sc, grd, i2hz, cnt);
  kan_i2h_gemm<<<1024, 512, 0, stream>>>(x, grd, Waug, hall);
  rnn_persist<<<256, 512, 0, stream>>>(WhhHi, WhhLo, i2hz, hbb, h0, hall, cnt);
  y_final<<<4096, 256, 0, stream>>>(hall, fcw, fcb, ypred);
}